// Round 3
// baseline (631.150 us; speedup 1.0000x reference)
//
#include <hip/hip_runtime.h>
#include <math.h>

// B=262144, N=1e6, R=64, H=128. Outputs: logits [B,2] then loss scalar.
//
// R3: decomposition from counters: dur 612 = poison fill (~317us, harness) +
// ~295us controllable. No restore copy exists (would show in top-5), so the
// fused gather kernel is ~200-270us vs a 43us traffic floor (268MB random
// 512B Wx rows). Both prior schedules (serial loop, pipelined straight-line)
// tie -> bottleneck is aggregate MLP / register pressure, not intra-wave
// order. This version: 3 tiny kernels.
//   K1: REW[64][128] = sigmoid'(clamp(Wr)) into ws (32KB, L2-hot) + zero loss
//   K2: PURE gather-dot, <=64 VGPR (__launch_bounds__(256,8)), depth-2
//       pipeline, 2048 blocks = exactly full residency. Per row: 3 loads,
//       12 FMA, 5 shfl, 1 store. No transcendentals, no divergent epilogue.
//   K3: streaming sigmoid/CE epilogue + atomicAdd loss (coalesced, ~3us).

#define H_DIM 128

// ---------------- K1: regularizer table + loss zero ----------------
__global__ __launch_bounds__(256) void prep_kernel(
    const float* __restrict__ Wr, float* __restrict__ REW,
    float* __restrict__ loss_out)
{
    for (int i = threadIdx.x; i < 64 * H_DIM; i += 256) {
        const float v = fminf(6.0f, fmaxf(-6.0f, Wr[i]));
        const float s = 1.0f / (1.0f + __expf(-v));
        REW[i] = s * (1.0f - s);
    }
    if (threadIdx.x == 0) *loss_out = 0.0f;
}

// ---------------- K2: pure gather-dot ----------------
#define GLOAD(it, av, bv, wv)                                          \
  {                                                                    \
    const int xi_ = __shfl(vxy, (it), 32);                             \
    const int yi_ = __shfl(vxy, 16 + (it), 32);                        \
    const int ri_ = __shfl(vr, (it), 32);                              \
    av = *(const float4*)(Wx + (size_t)xi_ * H_DIM + lane * 4);        \
    bv = *(const float4*)(Wx + (size_t)yi_ * H_DIM + lane * 4);        \
    wv = *(const float4*)(REW + (size_t)ri_ * H_DIM + lane * 4);       \
  }

#define GCOMP(it, av, bv, wv)                                          \
  {                                                                    \
    float d = (av).x * (bv).x * (wv).x + (av).y * (bv).y * (wv).y      \
            + (av).z * (bv).z * (wv).z + (av).w * (bv).w * (wv).w;     \
    d += __shfl_xor(d, 16, 64);                                        \
    d += __shfl_xor(d, 8, 64);                                         \
    d += __shfl_xor(d, 4, 64);                                         \
    d += __shfl_xor(d, 2, 64);                                         \
    d += __shfl_xor(d, 1, 64);                                         \
    if (lane == 0) dots[rbase + (it)] = d;                             \
  }

__global__ __launch_bounds__(256, 8) void gather_dot_kernel(
    const int* __restrict__ x, const int* __restrict__ y,
    const int* __restrict__ r, const float* __restrict__ Wx,
    const float* __restrict__ REW, float* __restrict__ dots, int B)
{
    const int group = threadIdx.x >> 5;                 // 8 groups of 32
    const int lane  = threadIdx.x & 31;
    const int rbase = blockIdx.x * 128 + group * 16;    // 16 rows per group

    // One coalesced index round-trip: lanes 0-15 x[rbase..+15], 16-31 y[...];
    // vr holds r[rbase..+15] (duplicated in upper half).
    int vxy = 0, vr = 0;
    {
        const int i = rbase + (lane & 15);
        if (i < B) {
            vxy = (lane < 16) ? x[i] : y[i];
            vr  = r[i];
        }
    }

    if (rbase + 16 <= B) {
        float4 a0, b0, w0, a1, b1, w1;
        GLOAD(0, a0, b0, w0)
        GLOAD(1, a1, b1, w1)
        #pragma unroll
        for (int it = 0; it < 14; it += 2) {
            GCOMP(it, a0, b0, w0)
            GLOAD(it + 2, a0, b0, w0)
            GCOMP(it + 1, a1, b1, w1)
            GLOAD(it + 3, a1, b1, w1)
        }
        GCOMP(14, a0, b0, w0)
        GCOMP(15, a1, b1, w1)
    } else if (rbase < B) {
        for (int it = 0; it < 16; ++it) {
            if (rbase + it >= B) break;
            float4 ta, tb, tw;
            GLOAD(it, ta, tb, tw)
            GCOMP(it, ta, tb, tw)
        }
    }
}

// ---------------- K3: epilogue (sigmoid, logits, CE loss) ----------------
__global__ __launch_bounds__(256) void epilogue_kernel(
    const float* __restrict__ dots, const int* __restrict__ l,
    float* __restrict__ logits, float* __restrict__ loss_out,
    int B, float invB)
{
    float acc = 0.0f;
    for (int i = blockIdx.x * 256 + threadIdx.x; i < B;
         i += gridDim.x * 256) {
        const float d = dots[i];
        const float p = 1.0f / (1.0f + __expf(-d));
        const float q = 1.0f - p;
        *(float2*)(logits + (size_t)i * 2) = make_float2(p, q);
        const float lse = __logf(__expf(p) + __expf(q));
        acc += lse - (l[i] == 0 ? p : q);
    }
    __shared__ float sd[256];
    sd[threadIdx.x] = acc;
    __syncthreads();
    for (int s = 128; s > 0; s >>= 1) {
        if ((int)threadIdx.x < s) sd[threadIdx.x] += sd[threadIdx.x + s];
        __syncthreads();
    }
    if (threadIdx.x == 0) atomicAdd(loss_out, sd[0] * invB);
}

extern "C" void kernel_launch(void* const* d_in, const int* in_sizes, int n_in,
                              void* d_out, int out_size, void* d_ws,
                              size_t ws_size, hipStream_t stream) {
    const int*   x  = (const int*)d_in[0];
    const int*   y  = (const int*)d_in[1];
    const int*   r  = (const int*)d_in[2];
    const int*   l  = (const int*)d_in[3];
    const float* Wx = (const float*)d_in[4];
    const float* Wr = (const float*)d_in[5];

    const int B = in_sizes[0];

    float* logits   = (float*)d_out;            // [B,2]
    float* loss_out = logits + (size_t)B * 2;   // scalar

    float* REW  = (float*)d_ws;                 // [64][128] = 32 KB
    float* dots = REW + 64 * H_DIM;             // [B] floats

    prep_kernel<<<1, 256, 0, stream>>>(Wr, REW, loss_out);

    const int NBLK = (B + 127) >> 7;            // 2048: exactly-full residency
    gather_dot_kernel<<<NBLK, 256, 0, stream>>>(x, y, r, Wx, REW, dots, B);

    epilogue_kernel<<<512, 256, 0, stream>>>(dots, l, logits, loss_out, B,
                                             1.0f / (float)B);
}

// Round 4
// 618.645 us; speedup vs baseline: 1.0202x; 1.0202x over previous
//
#include <hip/hip_runtime.h>
#include <math.h>

// B=262144, N=1e6, R=64, H=128. Outputs: logits [B,2] then loss scalar.
//
// R4: decisive structural test. Evidence: four different implementations
// (serial loop / pipelined / 3-kernel low-VGPR split) all land 606-631us,
// with the 2GB ws-poison fill (~317us) fixed. => our kernels are a small
// fraction of the timed region; slice is dominated by harness-owned work.
// This version minimizes everything we control: 2 dispatches total.
//   K1: fused. Per block: Wr -> sigmoid'(clamp) into LDS once (32KB, kills
//       the 3rd gather stream + all in-loop transcendentals), then 128 rows
//       (8 groups x 16 rows) of depth-2-pipelined Wx gathers, shfl-reduce,
//       lane0 sigmoid/CE epilogue, block partial.
//   K2: 1-block reduce of 2048 partials.
// Prediction: ties ~600-615us -> harness floor confirmed -> ROOFLINE.

#define H_DIM 128

#define GLOAD(it, av, bv, wv)                                          \
  {                                                                    \
    const int xi_ = __shfl(vxy, (it), 32);                             \
    const int yi_ = __shfl(vxy, 16 + (it), 32);                        \
    const int ri_ = __shfl(vr, (it), 32);                              \
    av = *(const float4*)(Wx + (size_t)xi_ * H_DIM + lane * 4);        \
    bv = *(const float4*)(Wx + (size_t)yi_ * H_DIM + lane * 4);        \
    wv = *(const float4*)(rew + ri_ * H_DIM + lane * 4);               \
  }

#define GCOMP(it, av, bv, wv)                                          \
  {                                                                    \
    const int li_ = __shfl(vl, (it), 32);                              \
    float d = (av).x * (bv).x * (wv).x + (av).y * (bv).y * (wv).y      \
            + (av).z * (bv).z * (wv).z + (av).w * (bv).w * (wv).w;     \
    d += __shfl_xor(d, 16, 64);                                        \
    d += __shfl_xor(d, 8, 64);                                         \
    d += __shfl_xor(d, 4, 64);                                         \
    d += __shfl_xor(d, 2, 64);                                         \
    d += __shfl_xor(d, 1, 64);                                         \
    if (lane == 0) {                                                   \
      const float p = 1.0f / (1.0f + __expf(-d));                      \
      const float q = 1.0f - p;                                        \
      *(float2*)(logits + (size_t)(rbase + (it)) * 2) =                \
          make_float2(p, q);                                           \
      const float lse = __logf(__expf(p) + __expf(q));                 \
      lossacc += lse - (li_ == 0 ? p : q);                             \
    }                                                                  \
  }

__global__ __launch_bounds__(256) void fused_kernel(
    const int* __restrict__ x, const int* __restrict__ y,
    const int* __restrict__ r, const int* __restrict__ l,
    const float* __restrict__ Wx, const float* __restrict__ Wr,
    float* __restrict__ logits, float* __restrict__ partials, int B)
{
    __shared__ float rew[64 * H_DIM];   // 32 KB: sigmoid'(clamp(Wr))
    __shared__ float sloss[8];

    // Per-block regularizer table (Wr is 32KB, L2-hot across 2048 blocks).
    for (int i = threadIdx.x; i < 64 * H_DIM / 4; i += 256) {
        const float4 w4 = ((const float4*)Wr)[i];
        float4 o;
        {
            const float v0 = fminf(6.0f, fmaxf(-6.0f, w4.x));
            const float v1 = fminf(6.0f, fmaxf(-6.0f, w4.y));
            const float v2 = fminf(6.0f, fmaxf(-6.0f, w4.z));
            const float v3 = fminf(6.0f, fmaxf(-6.0f, w4.w));
            const float s0 = 1.0f / (1.0f + __expf(-v0));
            const float s1 = 1.0f / (1.0f + __expf(-v1));
            const float s2 = 1.0f / (1.0f + __expf(-v2));
            const float s3 = 1.0f / (1.0f + __expf(-v3));
            o.x = s0 * (1.0f - s0);
            o.y = s1 * (1.0f - s1);
            o.z = s2 * (1.0f - s2);
            o.w = s3 * (1.0f - s3);
        }
        ((float4*)rew)[i] = o;
    }
    __syncthreads();

    const int group = threadIdx.x >> 5;                 // 8 groups of 32
    const int lane  = threadIdx.x & 31;
    const int rbase = blockIdx.x * 128 + group * 16;    // 16 rows per group

    float lossacc = 0.0f;

    // One coalesced index round-trip: lanes 0-15 hold x[rbase..+15],
    // lanes 16-31 hold y[...]; vr/vl hold r/l (dup in upper half).
    int vxy = 0, vr = 0, vl = 0;
    {
        const int i = rbase + (lane & 15);
        if (i < B) {
            vxy = (lane < 16) ? x[i] : y[i];
            vr  = r[i];
            vl  = l[i];
        }
    }

    if (rbase + 16 <= B) {
        float4 a0, b0, w0, a1, b1, w1;
        GLOAD(0, a0, b0, w0)
        GLOAD(1, a1, b1, w1)
        #pragma unroll
        for (int it = 0; it < 14; it += 2) {
            GCOMP(it, a0, b0, w0)
            GLOAD(it + 2, a0, b0, w0)
            GCOMP(it + 1, a1, b1, w1)
            GLOAD(it + 3, a1, b1, w1)
        }
        GCOMP(14, a0, b0, w0)
        GCOMP(15, a1, b1, w1)
    } else if (rbase < B) {
        for (int it = 0; it < 16; ++it) {
            if (rbase + it >= B) break;
            float4 ta, tb, tw;
            GLOAD(it, ta, tb, tw)
            GCOMP(it, ta, tb, tw)
        }
    }

    if (lane == 0) sloss[group] = lossacc;
    __syncthreads();
    if (threadIdx.x == 0) {
        float s = 0.0f;
        #pragma unroll
        for (int gi = 0; gi < 8; ++gi) s += sloss[gi];
        partials[blockIdx.x] = s;
    }
}

__global__ __launch_bounds__(256) void reduce_kernel(
    const float* __restrict__ partials, int n, float* __restrict__ out,
    double invB)
{
    __shared__ double sd[256];
    double acc = 0.0;
    for (int i = threadIdx.x; i < n; i += 256) acc += (double)partials[i];
    sd[threadIdx.x] = acc;
    __syncthreads();
    for (int s = 128; s > 0; s >>= 1) {
        if ((int)threadIdx.x < s) sd[threadIdx.x] += sd[threadIdx.x + s];
        __syncthreads();
    }
    if (threadIdx.x == 0) *out = (float)(sd[0] * invB);
}

extern "C" void kernel_launch(void* const* d_in, const int* in_sizes, int n_in,
                              void* d_out, int out_size, void* d_ws,
                              size_t ws_size, hipStream_t stream) {
    const int*   x  = (const int*)d_in[0];
    const int*   y  = (const int*)d_in[1];
    const int*   r  = (const int*)d_in[2];
    const int*   l  = (const int*)d_in[3];
    const float* Wx = (const float*)d_in[4];
    const float* Wr = (const float*)d_in[5];

    const int B = in_sizes[0];

    float* logits   = (float*)d_out;            // [B,2]
    float* loss_out = logits + (size_t)B * 2;   // scalar

    float* partials = (float*)d_ws;             // [NBLK]
    const int NBLK = (B + 127) >> 7;            // 2048 blocks x 128 rows

    fused_kernel<<<NBLK, 256, 0, stream>>>(x, y, r, l, Wx, Wr, logits,
                                           partials, B);
    reduce_kernel<<<1, 256, 0, stream>>>(partials, NBLK, loss_out,
                                         1.0 / (double)B);
}